// Round 8
// baseline (3803.350 us; speedup 1.0000x reference)
//
#include <hip/hip_runtime.h>
#include <hip/hip_bf16.h>

#define HID   512
#define SEQ   1024
#define GATES 2048       // 4*HID

// ---------------------------------------------------------------- helpers
__device__ __forceinline__ float sigm(float x) {
    return 1.f / (1.f + __expf(-x));
}
__device__ __forceinline__ float tanh_fast(float x) {
    float ax = fabsf(x);
    float e  = __expf(-2.f * ax);
    float t  = (1.f - e) * __builtin_amdgcn_rcpf(1.f + e);
    return copysignf(t, x);
}
__device__ __forceinline__ float bcast(float v, int l) {
    return __uint_as_float((unsigned)__builtin_amdgcn_readlane((int)__float_as_uint(v), l));
}
__device__ __forceinline__ unsigned long long pollLoad(const unsigned long long* p) {
    return __hip_atomic_load(p, __ATOMIC_RELAXED, __HIP_MEMORY_SCOPE_AGENT);
}

// ---------------------------------------------------------------- embedding
__global__ void embed_kernel(const int* __restrict__ wi, const int* __restrict__ pi,
                             const float* __restrict__ we, const float* __restrict__ pe,
                             float* __restrict__ x) {
    int i = blockIdx.x;          // token 0..1023
    int t = threadIdx.x;         // 128 threads
    const float* w = we + (size_t)wi[i] * 300;
    const float* p = pe + (size_t)pi[i] * 100;
    float* xo = x + (size_t)i * 400;
    for (int c = t; c < 300; c += 128) xo[c]       = w[c];
    for (int c = t; c < 100; c += 128) xo[300 + c] = p[c];
}

// ---------------------------------------------------------------- fp32 GEMM pair:
// z = blockIdx.z selects {B,bias,C}; C[M,N] = A[M,K] @ B[N,K]^T + bias[N].
// LDS tiles TRANSPOSED [k][row], stride 68 (b128-aligned reads; <=2-way write
// conflicts are free). Inner loop: 2x ds_read_b128 + 16 fma.
__global__ __launch_bounds__(256)
void gemm_bias2(const float* __restrict__ A,
                const float* __restrict__ B0, const float* __restrict__ bias0, float* __restrict__ C0,
                const float* __restrict__ B1, const float* __restrict__ bias1, float* __restrict__ C1,
                int M, int N, int K, int lda, int ldb, int ldc) {
    const float* B    = blockIdx.z ? B1    : B0;
    const float* bias = blockIdx.z ? bias1 : bias0;
    float*       C    = blockIdx.z ? C1    : C0;

    __shared__ __align__(16) float As[16 * 68];
    __shared__ __align__(16) float Bs[16 * 68];
    const int tid  = threadIdx.x;
    const int bn   = blockIdx.x, bm = blockIdx.y;
    const int tj   = tid & 15, ti = tid >> 4;
    const int lrow = tid >> 2;
    const int lk4  = (tid & 3) << 2;
    float acc[4][4] = {};

    for (int kt = 0; kt < K; kt += 16) {
        float4 av = *(const float4*)(A + (size_t)(bm * 64 + lrow) * lda + kt + lk4);
        float4 bv = *(const float4*)(B + (size_t)(bn * 64 + lrow) * ldb + kt + lk4);
        As[(lk4 + 0) * 68 + lrow] = av.x; As[(lk4 + 1) * 68 + lrow] = av.y;
        As[(lk4 + 2) * 68 + lrow] = av.z; As[(lk4 + 3) * 68 + lrow] = av.w;
        Bs[(lk4 + 0) * 68 + lrow] = bv.x; Bs[(lk4 + 1) * 68 + lrow] = bv.y;
        Bs[(lk4 + 2) * 68 + lrow] = bv.z; Bs[(lk4 + 3) * 68 + lrow] = bv.w;
        __syncthreads();
        #pragma unroll
        for (int k = 0; k < 16; ++k) {
            float4 a4 = *(const float4*)&As[k * 68 + ti * 4];
            float4 b4 = *(const float4*)&Bs[k * 68 + tj * 4];
            acc[0][0] = fmaf(a4.x, b4.x, acc[0][0]); acc[0][1] = fmaf(a4.x, b4.y, acc[0][1]);
            acc[0][2] = fmaf(a4.x, b4.z, acc[0][2]); acc[0][3] = fmaf(a4.x, b4.w, acc[0][3]);
            acc[1][0] = fmaf(a4.y, b4.x, acc[1][0]); acc[1][1] = fmaf(a4.y, b4.y, acc[1][1]);
            acc[1][2] = fmaf(a4.y, b4.z, acc[1][2]); acc[1][3] = fmaf(a4.y, b4.w, acc[1][3]);
            acc[2][0] = fmaf(a4.z, b4.x, acc[2][0]); acc[2][1] = fmaf(a4.z, b4.y, acc[2][1]);
            acc[2][2] = fmaf(a4.z, b4.z, acc[2][2]); acc[2][3] = fmaf(a4.z, b4.w, acc[2][3]);
            acc[3][0] = fmaf(a4.w, b4.x, acc[3][0]); acc[3][1] = fmaf(a4.w, b4.y, acc[3][1]);
            acc[3][2] = fmaf(a4.w, b4.z, acc[3][2]); acc[3][3] = fmaf(a4.w, b4.w, acc[3][3]);
        }
        __syncthreads();
    }
    const int n0 = bn * 64 + tj * 4;
    float bb0 = 0.f, bb1 = 0.f, bb2 = 0.f, bb3 = 0.f;
    if (bias) { bb0 = bias[n0]; bb1 = bias[n0 + 1]; bb2 = bias[n0 + 2]; bb3 = bias[n0 + 3]; }
    #pragma unroll
    for (int i = 0; i < 4; ++i) {
        float4 o;
        o.x = acc[i][0] + bb0; o.y = acc[i][1] + bb1;
        o.z = acc[i][2] + bb2; o.w = acc[i][3] + bb3;
        *(float4*)(C + (size_t)(bm * 64 + ti * 4 + i) * ldc + n0) = o;
    }
}

// ---------------------------------------------------------------- persistent bidirectional LSTM layer
// R7 structure + pipelined 4-slot poll.
// 64 WGs x 512 threads. WGs [0,32): forward; [32,64): reverse. Each WG owns 16
// hidden units = 64 gate rows. lane = gate row, wave = 64-wide k-chunk.
// Poll: 4 independent (tag<<32|bits) u64 loads kept in flight, checked
// round-robin — quadruples the IF sampling rate vs a serial spin.
__global__ __launch_bounds__(512)
void lstm_layer(const float* __restrict__ Zf, const float* __restrict__ Zr,
                const float* __restrict__ WhhF, const float* __restrict__ WhhR,
                unsigned long long* __restrict__ Hpair, // [SEQ][2*HID] (tag|h)
                float* __restrict__ Hout,               // [SEQ][2*HID] plain fp32
                unsigned tagBase) {
    const int dir = blockIdx.x >> 5;
    const int wg  = blockIdx.x & 31;
    const float* __restrict__ Z   = dir ? Zr   : Zf;
    const float* __restrict__ Whh = dir ? WhhR : WhhF;
    const int colOff = dir ? HID : 0;

    const int tid  = threadIdx.x;
    const int wave = tid >> 6;        // k-chunk 0..7 (h[64*wave .. +64))
    const int lane = tid & 63;        // local gate row 0..63
    const int g    = lane >> 4;       // gate 0..3 (i,f,g,o)
    const int jj   = lane & 15;       // local hidden unit 0..15
    const int grow = g * HID + wg * 16 + jj;   // row in Whh [2048 x 512]

    // this lane's 64 recurrent weights (k = wave*64 .. +64)
    float w[64];
    {
        const float4* wp = (const float4*)(Whh + (size_t)grow * HID + wave * 64);
        #pragma unroll
        for (int q = 0; q < 16; ++q) {
            float4 v = wp[q];
            w[4 * q] = v.x; w[4 * q + 1] = v.y; w[4 * q + 2] = v.z; w[4 * q + 3] = v.w;
        }
    }

    __shared__ float part[2][8 * 65];
    float cval = 0.f;                 // cell state (wave 0, lanes 0..15)

    for (int s = 0; s < SEQ; ++s) {
        const int t = dir ? (SEQ - 1 - s) : s;

        // wave 0 prefetches this row's input-projection z (overlaps the poll)
        float zin = 0.f;
        if (wave == 0) zin = Z[(size_t)t * GATES + grow];

        float acc = 0.f;
        if (s > 0) {
            const int tp = dir ? (t + 1) : (t - 1);
            const unsigned expTag = tagBase + (unsigned)s - 1u;
            const unsigned long long* hp = Hpair + (size_t)tp * (2 * HID) + colOff + wave * 64 + lane;
            unsigned long long v0 = pollLoad(hp), v1 = pollLoad(hp),
                               v2 = pollLoad(hp), v3 = pollLoad(hp);
            unsigned long long v;
            for (;;) {
                if (__all((unsigned)(v0 >> 32) == expTag)) { v = v0; break; }
                v0 = pollLoad(hp);
                if (__all((unsigned)(v1 >> 32) == expTag)) { v = v1; break; }
                v1 = pollLoad(hp);
                if (__all((unsigned)(v2 >> 32) == expTag)) { v = v2; break; }
                v2 = pollLoad(hp);
                if (__all((unsigned)(v3 >> 32) == expTag)) { v = v3; break; }
                v3 = pollLoad(hp);
            }
            float hv = __uint_as_float((unsigned)v);   // h[64*wave + lane]
            float a0 = 0.f, a1 = 0.f, a2 = 0.f, a3 = 0.f;
            #pragma unroll
            for (int m = 0; m < 64; m += 4) {
                a0 = fmaf(w[m + 0], bcast(hv, m + 0), a0);
                a1 = fmaf(w[m + 1], bcast(hv, m + 1), a1);
                a2 = fmaf(w[m + 2], bcast(hv, m + 2), a2);
                a3 = fmaf(w[m + 3], bcast(hv, m + 3), a3);
            }
            acc = (a0 + a1) + (a2 + a3);
        }
        part[s & 1][wave * 65 + lane] = acc;
        __syncthreads();   // waves 1..7 sprint ahead; wave 0 finishes the step

        if (wave == 0) {
            const float* pp = part[s & 1];
            float r = zin;
            #pragma unroll
            for (int c = 0; c < 8; ++c) r += pp[c * 65 + lane];
            // gather the 4 gates of unit jj (depth-1 shuffles)
            float zi = __shfl(r, jj);
            float zf = __shfl(r, 16 + jj);
            float zg = __shfl(r, 32 + jj);
            float zo = __shfl(r, 48 + jj);
            if (lane < 16) {
                float ig = sigm(zi), fg = sigm(zf), gg = tanh_fast(zg), og = sigm(zo);
                cval = fg * cval + ig * gg;
                float hv = og * tanh_fast(cval);
                const size_t oidx = (size_t)t * (2 * HID) + colOff + wg * 16 + lane;
                unsigned long long pk = ((unsigned long long)(tagBase + (unsigned)s) << 32)
                                      | (unsigned long long)__float_as_uint(hv);
                __hip_atomic_store(Hpair + oidx, pk, __ATOMIC_RELAXED, __HIP_MEMORY_SCOPE_AGENT);
                Hout[oidx] = hv;   // plain fp32 for downstream GEMMs (off critical path)
            }
        }
    }
}

// ---------------------------------------------------------------- pairwise MLP scores
__global__ __launch_bounds__(256)
void pairwise_kernel(const float* __restrict__ Ah, const float* __restrict__ Bd,
                     const float* __restrict__ w2, const float* __restrict__ b2,
                     float* __restrict__ out) {
    __shared__ __align__(16) float at[16 * 260];
    __shared__ __align__(16) float bt[16 * 260];
    __shared__ __align__(16) float wl[256];
    const int tid = threadIdx.x;
    const int i0 = blockIdx.y * 16, j0 = blockIdx.x * 16;
    for (int u = tid; u < 16 * 256; u += 256) {
        int r = u >> 8, m = u & 255;
        at[r * 260 + m] = Ah[(size_t)(i0 + r) * 256 + m];
        bt[r * 260 + m] = Bd[(size_t)(j0 + r) * 256 + m];
    }
    wl[tid] = w2[tid];
    __syncthreads();
    const int tj = tid & 15, ti = tid >> 4;
    float acc = b2[0];
    #pragma unroll 2
    for (int m = 0; m < 256; m += 4) {
        float4 a4 = *(const float4*)&at[ti * 260 + m];
        float4 b4 = *(const float4*)&bt[tj * 260 + m];
        float4 w4 = *(const float4*)&wl[m];
        acc += tanh_fast(a4.x + b4.x) * w4.x;
        acc += tanh_fast(a4.y + b4.y) * w4.y;
        acc += tanh_fast(a4.z + b4.z) * w4.z;
        acc += tanh_fast(a4.w + b4.w) * w4.w;
    }
    out[(size_t)(i0 + ti) * 1024 + (j0 + tj)] = acc;
}

// ---------------------------------------------------------------- launch
extern "C" void kernel_launch(void* const* d_in, const int* in_sizes, int n_in,
                              void* d_out, int out_size, void* d_ws, size_t ws_size,
                              hipStream_t stream) {
    const int*   wi    = (const int*)  d_in[0];
    const int*   pi    = (const int*)  d_in[1];
    const float* we    = (const float*)d_in[2];
    const float* pe    = (const float*)d_in[3];
    const float* wih0f = (const float*)d_in[4];
    const float* whh0f = (const float*)d_in[5];
    const float* b0f   = (const float*)d_in[6];
    const float* wih0r = (const float*)d_in[7];
    const float* whh0r = (const float*)d_in[8];
    const float* b0r   = (const float*)d_in[9];
    const float* wih1f = (const float*)d_in[10];
    const float* whh1f = (const float*)d_in[11];
    const float* b1f   = (const float*)d_in[12];
    const float* wih1r = (const float*)d_in[13];
    const float* whh1r = (const float*)d_in[14];
    const float* b1r   = (const float*)d_in[15];
    const float* W1    = (const float*)d_in[16];
    const float* bmlp1 = (const float*)d_in[17];
    const float* w2    = (const float*)d_in[18];
    const float* b2    = (const float*)d_in[19];
    float* out = (float*)d_out;

    char* wsb = (char*)d_ws;
    float* x  = (float*)(wsb + 512);          // 1024*400
    float* zA = x  + (size_t)1024 * 400;      // 1024*2048
    float* zB = zA + (size_t)1024 * 2048;     // 1024*2048
    float* h0 = zB + (size_t)1024 * 2048;     // 1024*1024
    float* h1 = h0 + (size_t)1024 * 1024;     // 1024*1024
    float* aH = h1 + (size_t)1024 * 1024;     // 1024*256
    float* bD = aH + (size_t)1024 * 256;      // 1024*256
    unsigned long long* Hpair = (unsigned long long*)(bD + (size_t)1024 * 256); // 1024*1024 u64

    embed_kernel<<<dim3(1024), dim3(128), 0, stream>>>(wi, pi, we, pe, x);

    // layer-0 input projections (both directions in one launch): [1024,400]@[2048,400]^T
    gemm_bias2<<<dim3(32, 16, 2), dim3(256), 0, stream>>>(
        x, wih0f, b0f, zA, wih0r, b0r, zB, 1024, 2048, 400, 400, 400, 2048);

    lstm_layer<<<dim3(64), dim3(512), 0, stream>>>(zA, zB, whh0f, whh0r, Hpair, h0, 1u);

    // layer-1 input projections (both directions): [1024,1024]@[2048,1024]^T
    gemm_bias2<<<dim3(32, 16, 2), dim3(256), 0, stream>>>(
        h0, wih1f, b1f, zA, wih1r, b1r, zB, 1024, 2048, 1024, 1024, 1024, 2048);

    lstm_layer<<<dim3(64), dim3(512), 0, stream>>>(zA, zB, whh1f, whh1r, Hpair, h1, 8192u);

    // head/dep projections (one launch): [1024,1024]@[256,1024]^T (bmlp1 folded into aH)
    gemm_bias2<<<dim3(4, 16, 2), dim3(256), 0, stream>>>(
        h1, W1, bmlp1, aH, W1 + 1024, nullptr, bD, 1024, 256, 1024, 1024, 2048, 256);

    pairwise_kernel<<<dim3(64, 64), dim3(256), 0, stream>>>(aH, bD, w2, b2, out);
}

// Round 9
// 3461.037 us; speedup vs baseline: 1.0989x; 1.0989x over previous
//
#include <hip/hip_runtime.h>
#include <hip/hip_bf16.h>

#define HID   512
#define SEQ   1024
#define GATES 2048       // 4*HID

// ---------------------------------------------------------------- helpers
__device__ __forceinline__ float sigm(float x) {
    return 1.f / (1.f + __expf(-x));
}
__device__ __forceinline__ float tanh_fast(float x) {
    float ax = fabsf(x);
    float e  = __expf(-2.f * ax);
    float t  = (1.f - e) * __builtin_amdgcn_rcpf(1.f + e);
    return copysignf(t, x);
}
__device__ __forceinline__ float bcast(float v, int l) {
    return __uint_as_float((unsigned)__builtin_amdgcn_readlane((int)__float_as_uint(v), l));
}

// ---------------------------------------------------------------- embedding
__global__ void embed_kernel(const int* __restrict__ wi, const int* __restrict__ pi,
                             const float* __restrict__ we, const float* __restrict__ pe,
                             float* __restrict__ x) {
    int i = blockIdx.x;          // token 0..1023
    int t = threadIdx.x;         // 128 threads
    const float* w = we + (size_t)wi[i] * 300;
    const float* p = pe + (size_t)pi[i] * 100;
    float* xo = x + (size_t)i * 400;
    for (int c = t; c < 300; c += 128) xo[c]       = w[c];
    for (int c = t; c < 100; c += 128) xo[300 + c] = p[c];
}

// ---------------------------------------------------------------- fp32 GEMM pair, 128x64 tile:
// blockIdx.z selects {B,bias,C}; C[M,N] = A[M,K] @ B[N,K]^T + bias[N].
// M mult of 128, N mult of 64, K mult of 16. 256 threads, 8x4 acc/thread.
// LDS TRANSPOSED [k][row] (A stride 132, B stride 68); inner: 3x ds_read_b128
// + 32 fma. Write conflicts <=2-way (free); A-read 4-way b128 (1.58x, ok).
__global__ __launch_bounds__(256)
void gemm_bias2(const float* __restrict__ A,
                const float* __restrict__ B0, const float* __restrict__ bias0, float* __restrict__ C0,
                const float* __restrict__ B1, const float* __restrict__ bias1, float* __restrict__ C1,
                int M, int N, int K, int lda, int ldb, int ldc) {
    const float* B    = blockIdx.z ? B1    : B0;
    const float* bias = blockIdx.z ? bias1 : bias0;
    float*       C    = blockIdx.z ? C1    : C0;

    __shared__ __align__(16) float As[16 * 132];
    __shared__ __align__(16) float Bs[16 * 68];
    const int tid  = threadIdx.x;
    const int bn   = blockIdx.x, bm = blockIdx.y;
    const int tj   = tid & 15, ti = tid >> 4;
    const int arow = tid >> 1;               // 0..127
    const int ak8  = (tid & 1) * 8;          // 0 or 8
    const int brow = tid >> 2;               // 0..63
    const int bk4  = (tid & 3) * 4;          // 0,4,8,12
    float acc[8][4] = {};

    for (int kt = 0; kt < K; kt += 16) {
        float4 a0 = *(const float4*)(A + (size_t)(bm * 128 + arow) * lda + kt + ak8);
        float4 a1 = *(const float4*)(A + (size_t)(bm * 128 + arow) * lda + kt + ak8 + 4);
        float4 bv = *(const float4*)(B + (size_t)(bn * 64 + brow) * ldb + kt + bk4);
        As[(ak8 + 0) * 132 + arow] = a0.x; As[(ak8 + 1) * 132 + arow] = a0.y;
        As[(ak8 + 2) * 132 + arow] = a0.z; As[(ak8 + 3) * 132 + arow] = a0.w;
        As[(ak8 + 4) * 132 + arow] = a1.x; As[(ak8 + 5) * 132 + arow] = a1.y;
        As[(ak8 + 6) * 132 + arow] = a1.z; As[(ak8 + 7) * 132 + arow] = a1.w;
        Bs[(bk4 + 0) * 68 + brow] = bv.x; Bs[(bk4 + 1) * 68 + brow] = bv.y;
        Bs[(bk4 + 2) * 68 + brow] = bv.z; Bs[(bk4 + 3) * 68 + brow] = bv.w;
        __syncthreads();
        #pragma unroll
        for (int k = 0; k < 16; ++k) {
            float4 x0 = *(const float4*)&As[k * 132 + ti * 8];
            float4 x1 = *(const float4*)&As[k * 132 + ti * 8 + 4];
            float4 b4 = *(const float4*)&Bs[k * 68 + tj * 4];
            const float av[8] = {x0.x, x0.y, x0.z, x0.w, x1.x, x1.y, x1.z, x1.w};
            #pragma unroll
            for (int i = 0; i < 8; ++i) {
                acc[i][0] = fmaf(av[i], b4.x, acc[i][0]);
                acc[i][1] = fmaf(av[i], b4.y, acc[i][1]);
                acc[i][2] = fmaf(av[i], b4.z, acc[i][2]);
                acc[i][3] = fmaf(av[i], b4.w, acc[i][3]);
            }
        }
        __syncthreads();
    }
    const int n0 = bn * 64 + tj * 4;
    float bb0 = 0.f, bb1 = 0.f, bb2 = 0.f, bb3 = 0.f;
    if (bias) { bb0 = bias[n0]; bb1 = bias[n0 + 1]; bb2 = bias[n0 + 2]; bb3 = bias[n0 + 3]; }
    #pragma unroll
    for (int i = 0; i < 8; ++i) {
        float4 o;
        o.x = acc[i][0] + bb0; o.y = acc[i][1] + bb1;
        o.z = acc[i][2] + bb2; o.w = acc[i][3] + bb3;
        *(float4*)(C + (size_t)(bm * 128 + ti * 8 + i) * ldc + n0) = o;
    }
}

// ---------------------------------------------------------------- persistent bidirectional LSTM layer
// R7 structure (best measured: single-load poll, double-buffered partials)
// + pre-gather nonlinearity in the epilogue.
// 64 WGs x 512 threads. WGs [0,32): forward; [32,64): reverse. Each WG owns 16
// hidden units = 64 gate rows. lane = gate row, wave = 64-wide k-chunk.
__global__ __launch_bounds__(512)
void lstm_layer(const float* __restrict__ Zf, const float* __restrict__ Zr,
                const float* __restrict__ WhhF, const float* __restrict__ WhhR,
                unsigned long long* __restrict__ Hpair, // [SEQ][2*HID] (tag|h)
                float* __restrict__ Hout,               // [SEQ][2*HID] plain fp32
                unsigned tagBase) {
    const int dir = blockIdx.x >> 5;
    const int wg  = blockIdx.x & 31;
    const float* __restrict__ Z   = dir ? Zr   : Zf;
    const float* __restrict__ Whh = dir ? WhhR : WhhF;
    const int colOff = dir ? HID : 0;

    const int tid  = threadIdx.x;
    const int wave = tid >> 6;        // k-chunk 0..7 (h[64*wave .. +64))
    const int lane = tid & 63;        // local gate row 0..63
    const int g    = lane >> 4;       // gate 0..3 (i,f,g,o)
    const int jj   = lane & 15;       // local hidden unit 0..15
    const int grow = g * HID + wg * 16 + jj;   // row in Whh [2048 x 512]

    // this lane's 64 recurrent weights (k = wave*64 .. +64)
    float w[64];
    {
        const float4* wp = (const float4*)(Whh + (size_t)grow * HID + wave * 64);
        #pragma unroll
        for (int q = 0; q < 16; ++q) {
            float4 v = wp[q];
            w[4 * q] = v.x; w[4 * q + 1] = v.y; w[4 * q + 2] = v.z; w[4 * q + 3] = v.w;
        }
    }

    __shared__ float part[2][8 * 65];
    float cval = 0.f;                 // cell state (wave 0, lanes 0..15)

    for (int s = 0; s < SEQ; ++s) {
        const int t = dir ? (SEQ - 1 - s) : s;

        // wave 0 prefetches this row's input-projection z (overlaps the poll)
        float zin = 0.f;
        if (wave == 0) zin = Z[(size_t)t * GATES + grow];

        float acc = 0.f;
        if (s > 0) {
            const int tp = dir ? (t + 1) : (t - 1);
            const unsigned expTag = tagBase + (unsigned)s - 1u;
            const unsigned long long* hp = Hpair + (size_t)tp * (2 * HID) + colOff + wave * 64;
            unsigned long long v;
            for (;;) {
                v = __hip_atomic_load(hp + lane, __ATOMIC_RELAXED, __HIP_MEMORY_SCOPE_AGENT);
                if (__all((unsigned)(v >> 32) == expTag)) break;
            }
            float hv = __uint_as_float((unsigned)v);   // h[64*wave + lane]
            float a0 = 0.f, a1 = 0.f, a2 = 0.f, a3 = 0.f;
            #pragma unroll
            for (int m = 0; m < 64; m += 4) {
                a0 = fmaf(w[m + 0], bcast(hv, m + 0), a0);
                a1 = fmaf(w[m + 1], bcast(hv, m + 1), a1);
                a2 = fmaf(w[m + 2], bcast(hv, m + 2), a2);
                a3 = fmaf(w[m + 3], bcast(hv, m + 3), a3);
            }
            acc = (a0 + a1) + (a2 + a3);
        }
        part[s & 1][wave * 65 + lane] = acc;
        __syncthreads();   // waves 1..7 sprint ahead; wave 0 finishes the step

        if (wave == 0) {
            const float* pp = part[s & 1];
            float r = zin;
            #pragma unroll
            for (int c = 0; c < 8; ++c) r += pp[c * 65 + lane];
            // apply this row's gate nonlinearity BEFORE the gather (parallel
            // across all 64 lanes; shortens the post-shuffle chain)
            float nl = (g == 2) ? tanh_fast(r) : sigm(r);
            // gather the 4 activated gates of unit jj (depth-1 shuffles)
            float ig = __shfl(nl, jj);
            float fg = __shfl(nl, 16 + jj);
            float gg = __shfl(nl, 32 + jj);
            float og = __shfl(nl, 48 + jj);
            if (lane < 16) {
                cval = fg * cval + ig * gg;
                float hv = og * tanh_fast(cval);
                const size_t oidx = (size_t)t * (2 * HID) + colOff + wg * 16 + lane;
                unsigned long long pk = ((unsigned long long)(tagBase + (unsigned)s) << 32)
                                      | (unsigned long long)__float_as_uint(hv);
                __hip_atomic_store(Hpair + oidx, pk, __ATOMIC_RELAXED, __HIP_MEMORY_SCOPE_AGENT);
                Hout[oidx] = hv;   // plain fp32 for downstream GEMMs (off critical path)
            }
        }
    }
}

// ---------------------------------------------------------------- pairwise MLP scores
__global__ __launch_bounds__(256)
void pairwise_kernel(const float* __restrict__ Ah, const float* __restrict__ Bd,
                     const float* __restrict__ w2, const float* __restrict__ b2,
                     float* __restrict__ out) {
    __shared__ __align__(16) float at[16 * 260];
    __shared__ __align__(16) float bt[16 * 260];
    __shared__ __align__(16) float wl[256];
    const int tid = threadIdx.x;
    const int i0 = blockIdx.y * 16, j0 = blockIdx.x * 16;
    for (int u = tid; u < 16 * 256; u += 256) {
        int r = u >> 8, m = u & 255;
        at[r * 260 + m] = Ah[(size_t)(i0 + r) * 256 + m];
        bt[r * 260 + m] = Bd[(size_t)(j0 + r) * 256 + m];
    }
    wl[tid] = w2[tid];
    __syncthreads();
    const int tj = tid & 15, ti = tid >> 4;
    float acc = b2[0];
    #pragma unroll 2
    for (int m = 0; m < 256; m += 4) {
        float4 a4 = *(const float4*)&at[ti * 260 + m];
        float4 b4 = *(const float4*)&bt[tj * 260 + m];
        float4 w4 = *(const float4*)&wl[m];
        acc += tanh_fast(a4.x + b4.x) * w4.x;
        acc += tanh_fast(a4.y + b4.y) * w4.y;
        acc += tanh_fast(a4.z + b4.z) * w4.z;
        acc += tanh_fast(a4.w + b4.w) * w4.w;
    }
    out[(size_t)(i0 + ti) * 1024 + (j0 + tj)] = acc;
}

// ---------------------------------------------------------------- launch
extern "C" void kernel_launch(void* const* d_in, const int* in_sizes, int n_in,
                              void* d_out, int out_size, void* d_ws, size_t ws_size,
                              hipStream_t stream) {
    const int*   wi    = (const int*)  d_in[0];
    const int*   pi    = (const int*)  d_in[1];
    const float* we    = (const float*)d_in[2];
    const float* pe    = (const float*)d_in[3];
    const float* wih0f = (const float*)d_in[4];
    const float* whh0f = (const float*)d_in[5];
    const float* b0f   = (const float*)d_in[6];
    const float* wih0r = (const float*)d_in[7];
    const float* whh0r = (const float*)d_in[8];
    const float* b0r   = (const float*)d_in[9];
    const float* wih1f = (const float*)d_in[10];
    const float* whh1f = (const float*)d_in[11];
    const float* b1f   = (const float*)d_in[12];
    const float* wih1r = (const float*)d_in[13];
    const float* whh1r = (const float*)d_in[14];
    const float* b1r   = (const float*)d_in[15];
    const float* W1    = (const float*)d_in[16];
    const float* bmlp1 = (const float*)d_in[17];
    const float* w2    = (const float*)d_in[18];
    const float* b2    = (const float*)d_in[19];
    float* out = (float*)d_out;

    char* wsb = (char*)d_ws;
    float* x  = (float*)(wsb + 512);          // 1024*400
    float* zA = x  + (size_t)1024 * 400;      // 1024*2048
    float* zB = zA + (size_t)1024 * 2048;     // 1024*2048
    float* h0 = zB + (size_t)1024 * 2048;     // 1024*1024
    float* h1 = h0 + (size_t)1024 * 1024;     // 1024*1024
    float* aH = h1 + (size_t)1024 * 1024;     // 1024*256
    float* bD = aH + (size_t)1024 * 256;      // 1024*256
    unsigned long long* Hpair = (unsigned long long*)(bD + (size_t)1024 * 256); // 1024*1024 u64

    embed_kernel<<<dim3(1024), dim3(128), 0, stream>>>(wi, pi, we, pe, x);

    // layer-0 input projections (both directions): [1024,400]@[2048,400]^T
    gemm_bias2<<<dim3(32, 8, 2), dim3(256), 0, stream>>>(
        x, wih0f, b0f, zA, wih0r, b0r, zB, 1024, 2048, 400, 400, 400, 2048);

    lstm_layer<<<dim3(64), dim3(512), 0, stream>>>(zA, zB, whh0f, whh0r, Hpair, h0, 1u);

    // layer-1 input projections (both directions): [1024,1024]@[2048,1024]^T
    gemm_bias2<<<dim3(32, 8, 2), dim3(256), 0, stream>>>(
        h0, wih1f, b1f, zA, wih1r, b1r, zB, 1024, 2048, 1024, 1024, 1024, 2048);

    lstm_layer<<<dim3(64), dim3(512), 0, stream>>>(zA, zB, whh1f, whh1r, Hpair, h1, 8192u);

    // head/dep projections (one launch): [1024,1024]@[256,1024]^T (bmlp1 folded into aH)
    gemm_bias2<<<dim3(4, 8, 2), dim3(256), 0, stream>>>(
        h1, W1, bmlp1, aH, W1 + 1024, nullptr, bD, 1024, 256, 1024, 1024, 2048, 256);

    pairwise_kernel<<<dim3(64, 64), dim3(256), 0, stream>>>(aH, bD, w2, b2, out);
}